// Round 1
// baseline (1766.931 us; speedup 1.0000x reference)
//
#include <hip/hip_runtime.h>
#include <hip/hip_bf16.h>

#define HD 128           // hidden dim
constexpr int KC = 64;   // k-chunk for GEMM staging

// ---------------------------------------------------------------------------
// Generic node GEMM: C[n][j] = act( sum_k A(n,k) * W[k][j] + bias[j]*scale )
// A is the concat of A1 (K1 cols) and optional A2 (K2 cols).
// If deg != null, bias is scaled per-row by deg[n] (for aggr = S@W2 + deg*b2).
// Tile: 64 rows x 128 cols per 256-thread block; 4x8 register tile per thread.
// ---------------------------------------------------------------------------
__global__ __launch_bounds__(256) void k_gemm(
    const float* __restrict__ A1, int K1,
    const float* __restrict__ A2, int K2,
    const float* __restrict__ W,
    const float* __restrict__ bias,
    const float* __restrict__ deg,
    int relu_flag,
    float* __restrict__ C, int nrows)
{
    __shared__ float Alt[KC][64];   // k-major (transposed) A tile
    __shared__ float Wl[KC][HD];
    const int tid = threadIdx.x;
    const int tx = tid & 15;        // output group: j0 = tx*8
    const int ty = tid >> 4;        // node group:   n0 = ty*4
    const int n_base = blockIdx.x * 64;

    float acc[4][8];
#pragma unroll
    for (int i = 0; i < 4; ++i)
#pragma unroll
        for (int j = 0; j < 8; ++j) acc[i][j] = 0.f;

    const int KTOT = K1 + K2;
    for (int k0 = 0; k0 < KTOT; k0 += KC) {
        // stage W chunk: KC*128 floats = 2048 float4
#pragma unroll
        for (int i = 0; i < 8; ++i) {
            int f = tid + i * 256;
            int kk = f >> 5;
            int jj = (f & 31) << 2;
            *(float4*)&Wl[kk][jj] = *(const float4*)&W[(size_t)(k0 + kk) * HD + jj];
        }
        // stage A chunk, transposed: 64 rows * KC = 1024 float4
        const float* Ap  = (k0 < K1) ? A1 : A2;
        const int   ks   = (k0 < K1) ? k0 : k0 - K1;
        const int   Krow = (k0 < K1) ? K1 : K2;
#pragma unroll
        for (int i = 0; i < 4; ++i) {
            int f = tid + i * 256;
            int nn = f >> 4;
            int kk = (f & 15) << 2;
            int row = n_base + nn;
            float4 v = make_float4(0.f, 0.f, 0.f, 0.f);
            if (row < nrows) v = *(const float4*)&Ap[(size_t)row * Krow + ks + kk];
            Alt[kk + 0][nn] = v.x;
            Alt[kk + 1][nn] = v.y;
            Alt[kk + 2][nn] = v.z;
            Alt[kk + 3][nn] = v.w;
        }
        __syncthreads();
#pragma unroll 8
        for (int k = 0; k < KC; ++k) {
            float4 a  = *(const float4*)&Alt[k][ty << 2];
            float4 w0 = *(const float4*)&Wl[k][tx << 3];
            float4 w1 = *(const float4*)&Wl[k][(tx << 3) + 4];
            float av[4] = {a.x, a.y, a.z, a.w};
            float wv[8] = {w0.x, w0.y, w0.z, w0.w, w1.x, w1.y, w1.z, w1.w};
#pragma unroll
            for (int i = 0; i < 4; ++i)
#pragma unroll
                for (int j = 0; j < 8; ++j)
                    acc[i][j] = fmaf(av[i], wv[j], acc[i][j]);
        }
        __syncthreads();
    }

    // epilogue
    float bj[8];
#pragma unroll
    for (int j = 0; j < 8; ++j) bj[j] = bias ? bias[(tx << 3) + j] : 0.f;
#pragma unroll
    for (int i = 0; i < 4; ++i) {
        int row = n_base + (ty << 2) + i;
        if (row >= nrows) continue;
        float sc = deg ? deg[row] : 1.f;
        float o[8];
#pragma unroll
        for (int j = 0; j < 8; ++j) {
            float v = acc[i][j] + bj[j] * sc;
            if (relu_flag) v = fmaxf(v, 0.f);
            o[j] = v;
        }
        *(float4*)&C[(size_t)row * HD + (tx << 3)]     = make_float4(o[0], o[1], o[2], o[3]);
        *(float4*)&C[(size_t)row * HD + (tx << 3) + 4] = make_float4(o[4], o[5], o[6], o[7]);
    }
}

// ---------------------------------------------------------------------------
// Edge kernel: t = relu(P[dst] + Q[src] + ea@W1c) ; S[dst] += t (atomic)
// 128 threads per edge (one output each), 2 edges per 256-thread block-iter.
// ---------------------------------------------------------------------------
__global__ __launch_bounds__(256) void k_edge(
    const float* __restrict__ P, const float* __restrict__ Q,
    const float* __restrict__ ea,
    const int* __restrict__ src, const int* __restrict__ dst,
    const float* __restrict__ W1c,   // [16][128]
    float* __restrict__ S, int E)
{
    __shared__ float Wl[16][HD];
    const int tid = threadIdx.x;
#pragma unroll
    for (int i = 0; i < 2; ++i) {
        int f = tid + i * 256;          // 512 float4 total
        int kk = f >> 5;
        int jj = (f & 31) << 2;
        *(float4*)&Wl[kk][jj] = *(const float4*)&W1c[(size_t)kk * HD + jj];
    }
    __syncthreads();
    const int j = tid & 127;
    const int sub = tid >> 7;
    for (int e = blockIdx.x * 2 + sub; e < E; e += gridDim.x * 2) {
        int s = src[e], d = dst[e];
        float t = P[(size_t)d * HD + j] + Q[(size_t)s * HD + j];
        const float4* eav = (const float4*)&ea[(size_t)e * 16];
#pragma unroll
        for (int k4 = 0; k4 < 4; ++k4) {
            float4 v = eav[k4];
            t = fmaf(v.x, Wl[k4 * 4 + 0][j], t);
            t = fmaf(v.y, Wl[k4 * 4 + 1][j], t);
            t = fmaf(v.z, Wl[k4 * 4 + 2][j], t);
            t = fmaf(v.w, Wl[k4 * 4 + 3][j], t);
        }
        t = fmaxf(t, 0.f);
        atomicAdd(&S[(size_t)d * HD + j], t);
    }
}

__global__ void k_deg(const int* __restrict__ dst, float* __restrict__ deg, int E)
{
    int e = blockIdx.x * blockDim.x + threadIdx.x;
    if (e < E) atomicAdd(&deg[dst[e]], 1.0f);
}

__global__ void k_count(const int* __restrict__ batch, float* __restrict__ cnt, int N)
{
    int n = blockIdx.x * blockDim.x + threadIdx.x;
    if (n < N) atomicAdd(&cnt[batch[n]], 1.0f);
}

// pool: per (node, j) atomics into gsum / gmax. h >= 0 so uint atomicMax is valid.
__global__ void k_pool(const float* __restrict__ h, const int* __restrict__ batch,
                       float* __restrict__ gsum, unsigned int* __restrict__ gmax, int N)
{
    int idx = blockIdx.x * blockDim.x + threadIdx.x;
    if (idx >= N * HD) return;
    int n = idx >> 7;
    int j = idx & 127;
    int g = batch[n];
    float v = h[(size_t)n * HD + j];
    atomicAdd(&gsum[(size_t)g * HD + j], v);
    atomicMax(&gmax[(size_t)g * HD + j], __float_as_uint(v));
}

// classifier: one block (128 threads) per graph
__global__ __launch_bounds__(128) void k_cls(
    const float* __restrict__ gsum, const float* __restrict__ gmax,
    const float* __restrict__ cnt,
    const float* __restrict__ W1, const float* __restrict__ b1,
    const float* __restrict__ W2, const float* __restrict__ b2,
    const float* __restrict__ W3, const float* __restrict__ b3,
    float* __restrict__ out, int G)
{
    __shared__ float rep[256];
    __shared__ float z1[128];
    __shared__ float z2[64];
    const int g = blockIdx.x;
    const int j = threadIdx.x;
    float inv = 1.f / fmaxf(cnt[g], 1.f);
    rep[j]       = gsum[(size_t)g * HD + j] * inv;
    rep[128 + j] = gmax[(size_t)g * HD + j];
    __syncthreads();
    float a = 0.f;
    for (int k = 0; k < 256; ++k) a = fmaf(rep[k], W1[(size_t)k * 128 + j], a);
    z1[j] = fmaxf(a + b1[j], 0.f);
    __syncthreads();
    if (j < 64) {
        float b = 0.f;
        for (int k = 0; k < 128; ++k) b = fmaf(z1[k], W2[(size_t)k * 64 + j], b);
        z2[j] = fmaxf(b + b2[j], 0.f);
    }
    __syncthreads();
    if (j < 2) {
        float c = 0.f;
        for (int k = 0; k < 64; ++k) c = fmaf(z2[k], W3[(size_t)k * 2 + j], c);
        out[(size_t)g * 2 + j] = c + b3[j];
    }
}

extern "C" void kernel_launch(void* const* d_in, const int* in_sizes, int n_in,
                              void* d_out, int out_size, void* d_ws, size_t ws_size,
                              hipStream_t stream) {
    const float* x      = (const float*)d_in[0];
    const float* ea     = (const float*)d_in[1];
    const int*   ei     = (const int*)d_in[2];
    const int*   batch  = (const int*)d_in[3];
    const float* emb_W  = (const float*)d_in[4];
    const float* emb_b  = (const float*)d_in[5];
    const float* msg_W1 = (const float*)d_in[6];
    const float* msg_b1 = (const float*)d_in[7];
    const float* msg_W2 = (const float*)d_in[8];
    const float* msg_b2 = (const float*)d_in[9];
    const float* upd_W1 = (const float*)d_in[10];
    const float* upd_b1 = (const float*)d_in[11];
    const float* upd_W2 = (const float*)d_in[12];
    const float* upd_b2 = (const float*)d_in[13];
    const float* cW1 = (const float*)d_in[14];
    const float* cb1 = (const float*)d_in[15];
    const float* cW2 = (const float*)d_in[16];
    const float* cb2 = (const float*)d_in[17];
    const float* cW3 = (const float*)d_in[18];
    const float* cb3 = (const float*)d_in[19];

    const int N = in_sizes[0] / 64;     // NODE_DIM=64
    const int E = in_sizes[1] / 16;     // EDGE_DIM=16
    const int G = 256, L = 3;
    const int* src = ei;
    const int* dst = ei + E;

    char* w = (char*)d_ws;
    size_t off = 0;
    auto alloc = [&](size_t bytes) -> void* {
        void* p = w + off;
        off += (bytes + 255) & ~(size_t)255;
        return p;
    };
    float* X0 = (float*)alloc((size_t)N * HD * 4);   // h
    float* X1 = (float*)alloc((size_t)N * HD * 4);   // P, then aggr
    float* X2 = (float*)alloc((size_t)N * HD * 4);   // Q, then U
    float* X3 = (float*)alloc((size_t)N * HD * 4);   // S
    float* deg  = (float*)alloc((size_t)N * 4);
    float* gsum = (float*)alloc((size_t)G * HD * 4);
    float* gmax = (float*)alloc((size_t)G * HD * 4);
    float* cnt  = (float*)alloc((size_t)G * 4);
    (void)ws_size; (void)n_in; (void)out_size;

    hipMemsetAsync(deg,  0, (size_t)N * 4, stream);
    hipMemsetAsync(gsum, 0, (size_t)G * HD * 4, stream);
    hipMemsetAsync(gmax, 0, (size_t)G * HD * 4, stream);
    hipMemsetAsync(cnt,  0, (size_t)G * 4, stream);

    k_deg<<<(E + 255) / 256, 256, 0, stream>>>(dst, deg, E);

    const int gb = (N + 63) / 64;
    // embed: h = x @ emb_W + emb_b  (no relu)
    k_gemm<<<gb, 256, 0, stream>>>(x, 64, nullptr, 0, emb_W, emb_b, nullptr, 0, X0, N);

    for (int l = 0; l < L; ++l) {
        const float* W1  = msg_W1 + (size_t)l * 272 * HD;
        const float* W2m = msg_W2 + (size_t)l * HD * HD;
        const float* U1  = upd_W1 + (size_t)l * 256 * HD;
        const float* U2  = upd_W2 + (size_t)l * HD * HD;
        // P = h @ W1[0:128] + b1   (dst / x_i part)
        k_gemm<<<gb, 256, 0, stream>>>(X0, HD, nullptr, 0, W1, msg_b1 + (size_t)l * HD,
                                       nullptr, 0, X1, N);
        // Q = h @ W1[128:256]      (src / x_j part)
        k_gemm<<<gb, 256, 0, stream>>>(X0, HD, nullptr, 0, W1 + 128 * HD, nullptr,
                                       nullptr, 0, X2, N);
        hipMemsetAsync(X3, 0, (size_t)N * HD * 4, stream);
        // S[dst] += relu(P[dst] + Q[src] + ea @ W1[256:272])
        k_edge<<<2048, 256, 0, stream>>>(X1, X2, ea, src, dst, W1 + 256 * HD, X3, E);
        // aggr = S @ W2 + deg * b2
        k_gemm<<<gb, 256, 0, stream>>>(X3, HD, nullptr, 0, W2m, msg_b2 + (size_t)l * HD,
                                       deg, 0, X1, N);
        // U = relu(h @ U1[0:128] + aggr @ U1[128:256] + b1u)
        k_gemm<<<gb, 256, 0, stream>>>(X0, HD, X1, HD, U1, upd_b1 + (size_t)l * HD,
                                       nullptr, 1, X2, N);
        // h = relu(U @ U2 + b2u)   (relu(relu(.)) == relu(.))
        k_gemm<<<gb, 256, 0, stream>>>(X2, HD, nullptr, 0, U2, upd_b2 + (size_t)l * HD,
                                       nullptr, 1, X0, N);
    }

    k_count<<<(N + 255) / 256, 256, 0, stream>>>(batch, cnt, N);
    k_pool<<<((size_t)N * HD + 255) / 256, 256, 0, stream>>>(X0, batch, gsum,
                                                             (unsigned int*)gmax, N);
    k_cls<<<G, 128, 0, stream>>>(gsum, gmax, cnt, cW1, cb1, cW2, cb2, cW3, cb3,
                                 (float*)d_out, G);
}

// Round 2
// 1262.574 us; speedup vs baseline: 1.3995x; 1.3995x over previous
//
#include <hip/hip_runtime.h>
#include <hip/hip_bf16.h>

#define HD 128

// ---------------------------------------------------------------------------
// Node GEMM. C[row][j] = act( sum_k A(row,k)*W[k][j] + bias[j]*scale(row) )
// A = [A1 | A2] (K1 + K2 cols). W given as Wlo (cols 0..127) / Whi (128..255).
// Block: 64 rows x NC cols, 256 threads, KC=32.
// LDS layouts tuned for bank-conflict-free compute reads:
//   As[k][row] padded to 65  -> staging writes <=2-way, compute reads broadcast
//   Ws[chunk][k][64]         -> compute reads 16 distinct consecutive 16B = free
// ---------------------------------------------------------------------------
template<int NC>
__global__ __launch_bounds__(256) void k_gemm(
    const float* __restrict__ A1, int K1,
    const float* __restrict__ A2, int K2,
    const float* __restrict__ Wlo, const float* __restrict__ Whi,
    const float* __restrict__ bias_lo, const float* __restrict__ bias_hi,
    const float* __restrict__ deg,
    int relu_flag,
    float* __restrict__ C, int ldc, int nrows)
{
    constexpr int KC  = 32;
    constexpr int CPT = NC / 16;   // cols per thread
    constexpr int NCH = CPT / 4;   // float4 chunks per thread
    __shared__ float As[KC][65];
    __shared__ float Ws[NCH][KC][64];

    const int tid = threadIdx.x;
    const int tx = tid & 15;
    const int ty = tid >> 4;
    const int n_base = blockIdx.x * 64;

    float acc[4][CPT];
#pragma unroll
    for (int i = 0; i < 4; ++i)
#pragma unroll
        for (int c = 0; c < CPT; ++c) acc[i][c] = 0.f;

    const int KTOT = K1 + K2;
    for (int k0 = 0; k0 < KTOT; k0 += KC) {
        // ---- stage W chunk: KC x NC floats ----
#pragma unroll
        for (int i = 0; i < NC / 32; ++i) {
            int f = tid + i * 256;
            int kk = f / (NC / 4);
            int jj = (f % (NC / 4)) * 4;
            const float* wsrc = (NC > 128 && jj >= 128) ? Whi : Wlo;
            float4 v = *(const float4*)&wsrc[(size_t)(k0 + kk) * HD + (jj & 127)];
            int c   = (jj % CPT) >> 2;
            int txp = jj / CPT;
            *(float4*)&Ws[c][kk][txp * 4] = v;
        }
        // ---- stage A chunk (transposed): 64 rows x KC ----
        const float* Ap = (k0 < K1) ? A1 : A2;
        const int ks    = (k0 < K1) ? k0 : k0 - K1;
        const int Krow  = (k0 < K1) ? K1 : K2;
#pragma unroll
        for (int i = 0; i < 2; ++i) {
            int f = tid + i * 256;
            int row = f >> 3;
            int kc  = f & 7;
            int grow = n_base + row;
            float4 v = make_float4(0.f, 0.f, 0.f, 0.f);
            if (grow < nrows) v = *(const float4*)&Ap[(size_t)grow * Krow + ks + kc * 4];
            As[kc * 4 + 0][row] = v.x;
            As[kc * 4 + 1][row] = v.y;
            As[kc * 4 + 2][row] = v.z;
            As[kc * 4 + 3][row] = v.w;
        }
        __syncthreads();
        // ---- compute ----
#pragma unroll 4
        for (int k = 0; k < KC; ++k) {
            float4 a = *(const float4*)&As[k][ty * 4];
            float av[4] = {a.x, a.y, a.z, a.w};
#pragma unroll
            for (int c = 0; c < NCH; ++c) {
                float4 w = *(const float4*)&Ws[c][k][tx * 4];
                float wv[4] = {w.x, w.y, w.z, w.w};
#pragma unroll
                for (int i2 = 0; i2 < 4; ++i2)
#pragma unroll
                    for (int q = 0; q < 4; ++q)
                        acc[i2][c * 4 + q] = fmaf(av[i2], wv[q], acc[i2][c * 4 + q]);
            }
        }
        __syncthreads();
    }

    // ---- epilogue ----
    float bj[CPT];
#pragma unroll
    for (int cc = 0; cc < CPT; ++cc) {
        int j = tx * CPT + cc;
        float b = 0.f;
        if (NC > 128 && j >= 128) { if (bias_hi) b = bias_hi[j - 128]; }
        else                      { if (bias_lo) b = bias_lo[j]; }
        bj[cc] = b;
    }
#pragma unroll
    for (int i = 0; i < 4; ++i) {
        int row = n_base + ty * 4 + i;
        if (row >= nrows) continue;
        float sc = deg ? deg[row] : 1.f;
#pragma unroll
        for (int c = 0; c < NCH; ++c) {
            float o[4];
#pragma unroll
            for (int q = 0; q < 4; ++q) {
                float v = acc[i][c * 4 + q] + bj[c * 4 + q] * sc;
                if (relu_flag) v = fmaxf(v, 0.f);
                o[q] = v;
            }
            *(float4*)&C[(size_t)row * ldc + tx * CPT + c * 4] =
                make_float4(o[0], o[1], o[2], o[3]);
        }
    }
}

// ---------------------------------------------------------------------------
// CSR build: deg -> rowptr (scan) -> scatter edge ids
// ---------------------------------------------------------------------------
__global__ void k_deg(const int* __restrict__ dst, int* __restrict__ degi, int E)
{
    int e = blockIdx.x * blockDim.x + threadIdx.x;
    if (e < E) atomicAdd(&degi[dst[e]], 1);
}

__global__ void k_hist(const int* __restrict__ batch, int* __restrict__ gcnt, int N)
{
    int n = blockIdx.x * blockDim.x + threadIdx.x;
    if (n < N) atomicAdd(&gcnt[batch[n]], 1);
}

__global__ __launch_bounds__(1024) void k_rowptr(
    const int* __restrict__ degi, int* __restrict__ rowptr,
    int* __restrict__ cursor, float* __restrict__ degf, int N)
{
    __shared__ int sc[1024];
    const int t = threadIdx.x;
    const int chunk = (N + 1023) >> 10;
    int lo = t * chunk;
    int hi = lo + chunk; if (hi > N) hi = N; if (lo > N) lo = N;
    int s = 0;
    for (int i = lo; i < hi; ++i) s += degi[i];
    sc[t] = s;
    __syncthreads();
    for (int off = 1; off < 1024; off <<= 1) {
        int v = (t >= off) ? sc[t - off] : 0;
        __syncthreads();
        sc[t] += v;
        __syncthreads();
    }
    int run = sc[t] - s;   // exclusive prefix
    for (int i = lo; i < hi; ++i) {
        int d = degi[i];
        rowptr[i] = run;
        cursor[i] = run;
        degf[i] = (float)d;
        run += d;
    }
    if (t == 1023) rowptr[N] = sc[1023];
}

__global__ __launch_bounds__(256) void k_gscan(
    const int* __restrict__ gcnt, int* __restrict__ gstart, int G)
{
    __shared__ int sc[256];
    const int t = threadIdx.x;
    sc[t] = gcnt[t];
    __syncthreads();
    for (int off = 1; off < 256; off <<= 1) {
        int v = (t >= off) ? sc[t - off] : 0;
        __syncthreads();
        sc[t] += v;
        __syncthreads();
    }
    gstart[t + 1] = sc[t];
    if (t == 0) gstart[0] = 0;
}

__global__ void k_scatter(const int* __restrict__ dst, const int* __restrict__ src,
                          int* __restrict__ cursor,
                          int* __restrict__ csr_src, int* __restrict__ csr_eid, int E)
{
    int e = blockIdx.x * blockDim.x + threadIdx.x;
    if (e < E) {
        int d = dst[e];
        int pos = atomicAdd(&cursor[d], 1);
        csr_src[pos] = src[e];
        csr_eid[pos] = e;
    }
}

// ---------------------------------------------------------------------------
// Edge gather kernel: S[n][:] = sum_{e: dst=n} relu(P[n] + Q[src] + ea[e]@W1c)
// One wave (64 lanes) per node, lane covers dims {lane, lane+64}.
// W1c kept in 32 registers per lane. No atomics, S written exactly once.
// ---------------------------------------------------------------------------
__global__ __launch_bounds__(256) void k_edge(
    const float* __restrict__ PQ,     // [N][256]: cols 0..127=P(+b1), 128..255=Q
    const float* __restrict__ ea,
    const int* __restrict__ rowptr,
    const int* __restrict__ csr_src,
    const int* __restrict__ csr_eid,
    const float* __restrict__ W1c,    // [16][128]
    float* __restrict__ S, int N)
{
    const int lane = threadIdx.x & 63;
    const int node = blockIdx.x * 4 + (threadIdx.x >> 6);
    if (node >= N) return;
    float wA[16], wB[16];
#pragma unroll
    for (int k = 0; k < 16; ++k) {
        wA[k] = W1c[k * HD + lane];
        wB[k] = W1c[k * HD + 64 + lane];
    }
    const int beg = rowptr[node], end = rowptr[node + 1];
    const float pA = PQ[(size_t)node * 256 + lane];
    const float pB = PQ[(size_t)node * 256 + 64 + lane];
    float accA = 0.f, accB = 0.f;
    for (int i = beg; i < end; ++i) {
        int s = csr_src[i];
        int e = csr_eid[i];
        float tA = pA + PQ[(size_t)s * 256 + 128 + lane];
        float tB = pB + PQ[(size_t)s * 256 + 192 + lane];
        const float4* eav = (const float4*)&ea[(size_t)e * 16];
#pragma unroll
        for (int k4 = 0; k4 < 4; ++k4) {
            float4 v = eav[k4];
            tA = fmaf(v.x, wA[k4 * 4 + 0], tA); tB = fmaf(v.x, wB[k4 * 4 + 0], tB);
            tA = fmaf(v.y, wA[k4 * 4 + 1], tA); tB = fmaf(v.y, wB[k4 * 4 + 1], tB);
            tA = fmaf(v.z, wA[k4 * 4 + 2], tA); tB = fmaf(v.z, wB[k4 * 4 + 2], tB);
            tA = fmaf(v.w, wA[k4 * 4 + 3], tA); tB = fmaf(v.w, wB[k4 * 4 + 3], tB);
        }
        accA += fmaxf(tA, 0.f);
        accB += fmaxf(tB, 0.f);
    }
    S[(size_t)node * HD + lane]      = accA;
    S[(size_t)node * HD + 64 + lane] = accB;
}

// ---------------------------------------------------------------------------
// Fused pool (segment mean/max over sorted batch) + classifier. Block = graph.
// ---------------------------------------------------------------------------
__global__ __launch_bounds__(128) void k_poolcls(
    const float* __restrict__ h, const int* __restrict__ gstart,
    const float* __restrict__ W1, const float* __restrict__ b1,
    const float* __restrict__ W2, const float* __restrict__ b2,
    const float* __restrict__ W3, const float* __restrict__ b3,
    float* __restrict__ out)
{
    __shared__ float rep[256];
    __shared__ float z1[128];
    __shared__ float z2[64];
    const int g = blockIdx.x;
    const int j = threadIdx.x;
    const int beg = gstart[g], end = gstart[g + 1];
    float s = 0.f, m = 0.f;      // h >= 0; empty graph -> 0 matches isfinite guard
    int n = beg;
    for (; n + 4 <= end; n += 4) {
        float v0 = h[(size_t)(n + 0) * HD + j];
        float v1 = h[(size_t)(n + 1) * HD + j];
        float v2 = h[(size_t)(n + 2) * HD + j];
        float v3 = h[(size_t)(n + 3) * HD + j];
        s += v0 + v1 + v2 + v3;
        m = fmaxf(m, fmaxf(fmaxf(v0, v1), fmaxf(v2, v3)));
    }
    for (; n < end; ++n) {
        float v = h[(size_t)n * HD + j];
        s += v; m = fmaxf(m, v);
    }
    float cntf = (float)(end - beg);
    rep[j]       = s / fmaxf(cntf, 1.f);
    rep[128 + j] = m;
    __syncthreads();
    float a = 0.f;
    for (int k = 0; k < 256; ++k) a = fmaf(rep[k], W1[(size_t)k * 128 + j], a);
    z1[j] = fmaxf(a + b1[j], 0.f);
    __syncthreads();
    if (j < 64) {
        float b = 0.f;
        for (int k = 0; k < 128; ++k) b = fmaf(z1[k], W2[(size_t)k * 64 + j], b);
        z2[j] = fmaxf(b + b2[j], 0.f);
    }
    __syncthreads();
    if (j < 2) {
        float c = 0.f;
        for (int k = 0; k < 64; ++k) c = fmaf(z2[k], W3[(size_t)k * 2 + j], c);
        out[(size_t)g * 2 + j] = c + b3[j];
    }
}

extern "C" void kernel_launch(void* const* d_in, const int* in_sizes, int n_in,
                              void* d_out, int out_size, void* d_ws, size_t ws_size,
                              hipStream_t stream) {
    const float* x      = (const float*)d_in[0];
    const float* ea     = (const float*)d_in[1];
    const int*   ei     = (const int*)d_in[2];
    const int*   batch  = (const int*)d_in[3];
    const float* emb_W  = (const float*)d_in[4];
    const float* emb_b  = (const float*)d_in[5];
    const float* msg_W1 = (const float*)d_in[6];
    const float* msg_b1 = (const float*)d_in[7];
    const float* msg_W2 = (const float*)d_in[8];
    const float* msg_b2 = (const float*)d_in[9];
    const float* upd_W1 = (const float*)d_in[10];
    const float* upd_b1 = (const float*)d_in[11];
    const float* upd_W2 = (const float*)d_in[12];
    const float* upd_b2 = (const float*)d_in[13];
    const float* cW1 = (const float*)d_in[14];
    const float* cb1 = (const float*)d_in[15];
    const float* cW2 = (const float*)d_in[16];
    const float* cb2 = (const float*)d_in[17];
    const float* cW3 = (const float*)d_in[18];
    const float* cb3 = (const float*)d_in[19];

    const int N = in_sizes[0] / 64;
    const int E = in_sizes[1] / 16;
    const int G = 256, L = 3;
    const int* src = ei;
    const int* dst = ei + E;

    char* w = (char*)d_ws;
    size_t off = 0;
    auto alloc = [&](size_t bytes) -> void* {
        void* p = w + off;
        off += (bytes + 255) & ~(size_t)255;
        return p;
    };
    float* X0   = (float*)alloc((size_t)N * HD * 4);    // h
    float* PQ   = (float*)alloc((size_t)N * 256 * 4);   // [P|Q]; first half reused as U
    float* S    = (float*)alloc((size_t)N * HD * 4);    // edge aggregation; aggr in-place
    int*   degi = (int*)alloc((size_t)N * 4);
    float* degf = (float*)alloc((size_t)N * 4);
    int*   rowptr = (int*)alloc((size_t)(N + 1) * 4);
    int*   cursor = (int*)alloc((size_t)N * 4);
    int*   gcnt   = (int*)alloc(256 * 4);
    int*   gstart = (int*)alloc(257 * 4);
    int*   csr_src = (int*)alloc((size_t)E * 4);
    int*   csr_eid = (int*)alloc((size_t)E * 4);
    float* U = PQ;   // upd hidden reuses PQ space
    (void)ws_size; (void)n_in; (void)out_size;

    hipMemsetAsync(degi, 0, (size_t)N * 4, stream);
    hipMemsetAsync(gcnt, 0, 256 * 4, stream);

    // CSR build (reused by all 3 layers) + graph segment boundaries
    k_deg<<<(E + 255) / 256, 256, 0, stream>>>(dst, degi, E);
    k_hist<<<(N + 255) / 256, 256, 0, stream>>>(batch, gcnt, N);
    k_rowptr<<<1, 1024, 0, stream>>>(degi, rowptr, cursor, degf, N);
    k_gscan<<<1, 256, 0, stream>>>(gcnt, gstart, G);
    k_scatter<<<(E + 255) / 256, 256, 0, stream>>>(dst, src, cursor, csr_src, csr_eid, E);

    const int gb = (N + 63) / 64;
    // embed: h = x @ emb_W + emb_b
    k_gemm<128><<<gb, 256, 0, stream>>>(x, 64, nullptr, 0, emb_W, nullptr,
                                        emb_b, nullptr, nullptr, 0, X0, HD, N);

    for (int l = 0; l < L; ++l) {
        const float* W1  = msg_W1 + (size_t)l * 272 * HD;   // rows: [0:128)=Wa,[128:256)=Wb,[256:272)=Wc
        const float* W2m = msg_W2 + (size_t)l * HD * HD;
        const float* U1  = upd_W1 + (size_t)l * 256 * HD;
        const float* U2  = upd_W2 + (size_t)l * HD * HD;
        // PQ = [ h@Wa + b1 | h@Wb ]
        k_gemm<256><<<gb, 256, 0, stream>>>(X0, HD, nullptr, 0, W1, W1 + 128 * HD,
                                            msg_b1 + (size_t)l * HD, nullptr,
                                            nullptr, 0, PQ, 256, N);
        // S[n] = sum_in relu(P[n] + Q[src] + ea@Wc)
        k_edge<<<(N + 3) / 4, 256, 0, stream>>>(PQ, ea, rowptr, csr_src, csr_eid,
                                                W1 + 256 * HD, S, N);
        // aggr = S @ W2 + deg*b2   (in-place: each block reads/writes its own stripe)
        k_gemm<128><<<gb, 256, 0, stream>>>(S, HD, nullptr, 0, W2m, nullptr,
                                            msg_b2 + (size_t)l * HD, nullptr,
                                            degf, 0, S, HD, N);
        // U = relu([h|aggr] @ U1 + b1u)
        k_gemm<128><<<gb, 256, 0, stream>>>(X0, HD, S, HD, U1, nullptr,
                                            upd_b1 + (size_t)l * HD, nullptr,
                                            nullptr, 1, U, HD, N);
        // h = relu(U @ U2 + b2u)
        k_gemm<128><<<gb, 256, 0, stream>>>(U, HD, nullptr, 0, U2, nullptr,
                                            upd_b2 + (size_t)l * HD, nullptr,
                                            nullptr, 1, X0, HD, N);
    }

    k_poolcls<<<G, 128, 0, stream>>>(X0, gstart, cW1, cb1, cW2, cb2, cW3, cb3,
                                     (float*)d_out);
}

// Round 4
// 1191.478 us; speedup vs baseline: 1.4830x; 1.0597x over previous
//
#include <hip/hip_runtime.h>
#include <hip/hip_bf16.h>

#define HD 128

// ---------------------------------------------------------------------------
// Node GEMM. C[row][j] = act( sum_k [A1|A2](row,k)*W[k][j] + bias_lo[j]
//                             + deg[row]*bias_deg[j] )
// NC=256 writes cols 0..127 -> C, 128..255 -> C2 (both ld = 128).
// ---------------------------------------------------------------------------
template<int NC>
__global__ __launch_bounds__(256) void k_gemm(
    const float* __restrict__ A1, int K1,
    const float* __restrict__ A2, int K2,
    const float* __restrict__ Wlo, const float* __restrict__ Whi,
    const float* __restrict__ bias_lo,
    const float* __restrict__ bias_deg, const float* __restrict__ deg,
    int relu_flag,
    float* __restrict__ C, float* __restrict__ C2, int nrows)
{
    constexpr int KC  = 32;
    constexpr int CPT = NC / 16;   // cols per thread
    constexpr int NCH = CPT / 4;   // float4 chunks per thread
    __shared__ float As[KC][65];
    __shared__ float Ws[NCH][KC][64];

    const int tid = threadIdx.x;
    const int tx = tid & 15;
    const int ty = tid >> 4;
    const int n_base = blockIdx.x * 64;

    float acc[4][CPT];
#pragma unroll
    for (int i = 0; i < 4; ++i)
#pragma unroll
        for (int c = 0; c < CPT; ++c) acc[i][c] = 0.f;

    const int KTOT = K1 + K2;
    for (int k0 = 0; k0 < KTOT; k0 += KC) {
#pragma unroll
        for (int i = 0; i < NC / 32; ++i) {
            int f = tid + i * 256;
            int kk = f / (NC / 4);
            int jj = (f % (NC / 4)) * 4;
            const float* wsrc = (NC > 128 && jj >= 128) ? Whi : Wlo;
            float4 v = *(const float4*)&wsrc[(size_t)(k0 + kk) * HD + (jj & 127)];
            int c   = (jj % CPT) >> 2;
            int txp = jj / CPT;
            *(float4*)&Ws[c][kk][txp * 4] = v;
        }
        const float* Ap = (k0 < K1) ? A1 : A2;
        const int ks    = (k0 < K1) ? k0 : k0 - K1;
        const int Krow  = (k0 < K1) ? K1 : K2;
#pragma unroll
        for (int i = 0; i < 2; ++i) {
            int f = tid + i * 256;
            int row = f >> 3;
            int kc  = f & 7;
            int grow = n_base + row;
            float4 v = make_float4(0.f, 0.f, 0.f, 0.f);
            if (grow < nrows) v = *(const float4*)&Ap[(size_t)grow * Krow + ks + kc * 4];
            As[kc * 4 + 0][row] = v.x;
            As[kc * 4 + 1][row] = v.y;
            As[kc * 4 + 2][row] = v.z;
            As[kc * 4 + 3][row] = v.w;
        }
        __syncthreads();
#pragma unroll 4
        for (int k = 0; k < KC; ++k) {
            float4 a = *(const float4*)&As[k][ty * 4];
            float av[4] = {a.x, a.y, a.z, a.w};
#pragma unroll
            for (int c = 0; c < NCH; ++c) {
                float4 w = *(const float4*)&Ws[c][k][tx * 4];
                float wv[4] = {w.x, w.y, w.z, w.w};
#pragma unroll
                for (int i2 = 0; i2 < 4; ++i2)
#pragma unroll
                    for (int q = 0; q < 4; ++q)
                        acc[i2][c * 4 + q] = fmaf(av[i2], wv[q], acc[i2][c * 4 + q]);
            }
        }
        __syncthreads();
    }

    float bj[CPT], bd[CPT];
#pragma unroll
    for (int cc = 0; cc < CPT; ++cc) {
        int j = tx * CPT + cc;
        bj[cc] = (j < 128 && bias_lo) ? bias_lo[j] : 0.f;
        bd[cc] = (j < 128 && bias_deg) ? bias_deg[j] : 0.f;
    }
#pragma unroll
    for (int i = 0; i < 4; ++i) {
        int row = n_base + ty * 4 + i;
        if (row >= nrows) continue;
        float sc = deg ? deg[row] : 0.f;
#pragma unroll
        for (int c = 0; c < NCH; ++c) {
            int jbase = tx * CPT + c * 4;
            float o[4];
#pragma unroll
            for (int q = 0; q < 4; ++q) {
                float v = acc[i][c * 4 + q] + bj[c * 4 + q] + sc * bd[c * 4 + q];
                if (relu_flag) v = fmaxf(v, 0.f);
                o[q] = v;
            }
            float* Cout = C; int jc = jbase;
            if (NC > 128 && jbase >= 128) { Cout = C2; jc = jbase - 128; }
            *(float4*)&Cout[(size_t)row * HD + jc] = make_float4(o[0], o[1], o[2], o[3]);
        }
    }
}

// ---------------------------------------------------------------------------
// CSR build
// ---------------------------------------------------------------------------
__global__ void k_deg(const int* __restrict__ dst, int* __restrict__ degi, int E)
{
    int e = blockIdx.x * blockDim.x + threadIdx.x;
    if (e < E) atomicAdd(&degi[dst[e]], 1);
}

__global__ void k_hist(const int* __restrict__ batch, int* __restrict__ gcnt, int N)
{
    int n = blockIdx.x * blockDim.x + threadIdx.x;
    if (n < N) atomicAdd(&gcnt[batch[n]], 1);
}

__global__ __launch_bounds__(1024) void k_rowptr(
    const int* __restrict__ degi, int* __restrict__ rowptr,
    int* __restrict__ cursor, float* __restrict__ degf, int N)
{
    __shared__ int sc[1024];
    const int t = threadIdx.x;
    const int chunk = (N + 1023) >> 10;
    int lo = t * chunk;
    int hi = lo + chunk; if (hi > N) hi = N; if (lo > N) lo = N;
    int s = 0;
    for (int i = lo; i < hi; ++i) s += degi[i];
    sc[t] = s;
    __syncthreads();
    for (int off = 1; off < 1024; off <<= 1) {
        int v = (t >= off) ? sc[t - off] : 0;
        __syncthreads();
        sc[t] += v;
        __syncthreads();
    }
    int run = sc[t] - s;
    for (int i = lo; i < hi; ++i) {
        int d = degi[i];
        rowptr[i] = run;
        cursor[i] = run;
        degf[i] = (float)d;
        run += d;
    }
    if (t == 1023) rowptr[N] = sc[1023];
}

__global__ void k_scatter(const int* __restrict__ dst, const int* __restrict__ src,
                          int* __restrict__ cursor,
                          int* __restrict__ csr_src, int* __restrict__ csr_eid, int E)
{
    int e = blockIdx.x * blockDim.x + threadIdx.x;
    if (e < E) {
        int d = dst[e];
        int pos = atomicAdd(&cursor[d], 1);
        csr_src[pos] = src[e];
        csr_eid[pos] = e;
    }
}

// permute edge_attr into CSR order (once; reused by all layers)
__global__ void k_permEA(const float* __restrict__ ea, const int* __restrict__ csr_eid,
                         float* __restrict__ ea_p, int E)
{
    long long gid = (long long)blockIdx.x * blockDim.x + threadIdx.x;
    if (gid >= (long long)E * 4) return;
    int pos = (int)(gid >> 2), part = (int)(gid & 3);
    int e = csr_eid[pos];
    ((float4*)ea_p)[(size_t)pos * 4 + part] = ((const float4*)ea)[(size_t)e * 4 + part];
}

// ---------------------------------------------------------------------------
// Weight folds: Wcomb rows 128..255 = W2 @ U1b ; bvec2 = b2 @ U1b
// ---------------------------------------------------------------------------
__global__ __launch_bounds__(256) void k_foldW(
    const float* __restrict__ msg_W2, const float* __restrict__ upd_W1,
    float* __restrict__ Wcomb)
{
    int l = blockIdx.x >> 3, rb = blockIdx.x & 7;
    const float* W2  = msg_W2 + (size_t)l * HD * HD;
    const float* U1b = upd_W1 + (size_t)l * 256 * HD + (size_t)HD * HD;
    float* Wout = Wcomb + (size_t)l * 256 * HD + (size_t)HD * HD;
    int j = threadIdx.x & 127;
    int rh = threadIdx.x >> 7;
    int r0 = rb * 16 + rh * 8;
    float acc[8] = {0.f,0.f,0.f,0.f,0.f,0.f,0.f,0.f};
    for (int k = 0; k < HD; ++k) {
        float u = U1b[(size_t)k * HD + j];
#pragma unroll
        for (int rr = 0; rr < 8; ++rr)
            acc[rr] = fmaf(W2[(size_t)(r0 + rr) * HD + k], u, acc[rr]);
    }
#pragma unroll
    for (int rr = 0; rr < 8; ++rr)
        Wout[(size_t)(r0 + rr) * HD + j] = acc[rr];
}

__global__ __launch_bounds__(128) void k_foldb(
    const float* __restrict__ msg_b2, const float* __restrict__ upd_W1,
    float* __restrict__ bvec2)
{
    int l = blockIdx.x, j = threadIdx.x;
    const float* U1b = upd_W1 + (size_t)l * 256 * HD + (size_t)HD * HD;
    const float* b2 = msg_b2 + (size_t)l * HD;
    float acc = 0.f;
    for (int k = 0; k < HD; ++k) acc = fmaf(b2[k], U1b[(size_t)k * HD + j], acc);
    bvec2[(size_t)l * HD + j] = acc;
}

// ---------------------------------------------------------------------------
// Edge gather: S[n] = sum_{e:dst=n} relu(P[n] + Q[src] + ea@Wc)
// wave per node; 4-edge unroll batches the gather latency.
// ---------------------------------------------------------------------------
template<bool PERM>
__global__ __launch_bounds__(256) void k_edge(
    const float* __restrict__ P, const float* __restrict__ Q,
    const float* __restrict__ EA,          // PERM: csr-order; else edge-id order
    const int* __restrict__ rowptr,
    const int* __restrict__ csr_src, const int* __restrict__ csr_eid,
    const float* __restrict__ W1c,
    float* __restrict__ S, int N)
{
    const int lane = threadIdx.x & 63;
    const int node = blockIdx.x * 4 + (threadIdx.x >> 6);
    if (node >= N) return;
    float wA[16], wB[16];
#pragma unroll
    for (int k = 0; k < 16; ++k) {
        wA[k] = W1c[k * HD + lane];
        wB[k] = W1c[k * HD + 64 + lane];
    }
    const int beg = rowptr[node], end = rowptr[node + 1];
    const float pA = P[(size_t)node * HD + lane];
    const float pB = P[(size_t)node * HD + 64 + lane];
    float accA = 0.f, accB = 0.f;

    int i = beg;
    for (; i + 4 <= end; i += 4) {
        int s[4];
        s[0] = csr_src[i]; s[1] = csr_src[i + 1];
        s[2] = csr_src[i + 2]; s[3] = csr_src[i + 3];
        float qA[4], qB[4];
#pragma unroll
        for (int r = 0; r < 4; ++r) {
            qA[r] = Q[(size_t)s[r] * HD + lane];
            qB[r] = Q[(size_t)s[r] * HD + 64 + lane];
        }
#pragma unroll
        for (int r = 0; r < 4; ++r) {
            const float4* Ev = PERM ? (const float4*)&EA[(size_t)(i + r) * 16]
                                    : (const float4*)&EA[(size_t)csr_eid[i + r] * 16];
            float4 v0 = Ev[0], v1 = Ev[1], v2 = Ev[2], v3 = Ev[3];
            float tA = pA + qA[r], tB = pB + qB[r];
            tA = fmaf(v0.x, wA[0],  tA); tB = fmaf(v0.x, wB[0],  tB);
            tA = fmaf(v0.y, wA[1],  tA); tB = fmaf(v0.y, wB[1],  tB);
            tA = fmaf(v0.z, wA[2],  tA); tB = fmaf(v0.z, wB[2],  tB);
            tA = fmaf(v0.w, wA[3],  tA); tB = fmaf(v0.w, wB[3],  tB);
            tA = fmaf(v1.x, wA[4],  tA); tB = fmaf(v1.x, wB[4],  tB);
            tA = fmaf(v1.y, wA[5],  tA); tB = fmaf(v1.y, wB[5],  tB);
            tA = fmaf(v1.z, wA[6],  tA); tB = fmaf(v1.z, wB[6],  tB);
            tA = fmaf(v1.w, wA[7],  tA); tB = fmaf(v1.w, wB[7],  tB);
            tA = fmaf(v2.x, wA[8],  tA); tB = fmaf(v2.x, wB[8],  tB);
            tA = fmaf(v2.y, wA[9],  tA); tB = fmaf(v2.y, wB[9],  tB);
            tA = fmaf(v2.z, wA[10], tA); tB = fmaf(v2.z, wB[10], tB);
            tA = fmaf(v2.w, wA[11], tA); tB = fmaf(v2.w, wB[11], tB);
            tA = fmaf(v3.x, wA[12], tA); tB = fmaf(v3.x, wB[12], tB);
            tA = fmaf(v3.y, wA[13], tA); tB = fmaf(v3.y, wB[13], tB);
            tA = fmaf(v3.z, wA[14], tA); tB = fmaf(v3.z, wB[14], tB);
            tA = fmaf(v3.w, wA[15], tA); tB = fmaf(v3.w, wB[15], tB);
            accA += fmaxf(tA, 0.f);
            accB += fmaxf(tB, 0.f);
        }
    }
    for (; i < end; ++i) {
        int s0 = csr_src[i];
        float qA0 = Q[(size_t)s0 * HD + lane];
        float qB0 = Q[(size_t)s0 * HD + 64 + lane];
        const float4* Ev = PERM ? (const float4*)&EA[(size_t)i * 16]
                                : (const float4*)&EA[(size_t)csr_eid[i] * 16];
        float4 v0 = Ev[0], v1 = Ev[1], v2 = Ev[2], v3 = Ev[3];
        float tA = pA + qA0, tB = pB + qB0;
        tA = fmaf(v0.x, wA[0],  tA); tB = fmaf(v0.x, wB[0],  tB);
        tA = fmaf(v0.y, wA[1],  tA); tB = fmaf(v0.y, wB[1],  tB);
        tA = fmaf(v0.z, wA[2],  tA); tB = fmaf(v0.z, wB[2],  tB);
        tA = fmaf(v0.w, wA[3],  tA); tB = fmaf(v0.w, wB[3],  tB);
        tA = fmaf(v1.x, wA[4],  tA); tB = fmaf(v1.x, wB[4],  tB);
        tA = fmaf(v1.y, wA[5],  tA); tB = fmaf(v1.y, wB[5],  tB);
        tA = fmaf(v1.z, wA[6],  tA); tB = fmaf(v1.z, wB[6],  tB);
        tA = fmaf(v1.w, wA[7],  tA); tB = fmaf(v1.w, wB[7],  tB);
        tA = fmaf(v2.x, wA[8],  tA); tB = fmaf(v2.x, wB[8],  tB);
        tA = fmaf(v2.y, wA[9],  tA); tB = fmaf(v2.y, wB[9],  tB);
        tA = fmaf(v2.z, wA[10], tA); tB = fmaf(v2.z, wB[10], tB);
        tA = fmaf(v2.w, wA[11], tA); tB = fmaf(v2.w, wB[11], tB);
        tA = fmaf(v3.x, wA[12], tA); tB = fmaf(v3.x, wB[12], tB);
        tA = fmaf(v3.y, wA[13], tA); tB = fmaf(v3.y, wB[13], tB);
        tA = fmaf(v3.z, wA[14], tA); tB = fmaf(v3.z, wB[14], tB);
        tA = fmaf(v3.w, wA[15], tA); tB = fmaf(v3.w, wB[15], tB);
        accA += fmaxf(tA, 0.f);
        accB += fmaxf(tB, 0.f);
    }
    S[(size_t)node * HD + lane]      = accA;
    S[(size_t)node * HD + 64 + lane] = accB;
}

// ---------------------------------------------------------------------------
// Pool: wide segment sum/max (batch sorted). Then classifier per graph.
// ---------------------------------------------------------------------------
__global__ __launch_bounds__(256) void k_pool2(
    const float* __restrict__ h, const int* __restrict__ batch,
    float* __restrict__ gsum, unsigned int* __restrict__ gmax, int N)
{
    int nchunk = (N + gridDim.x - 1) / gridDim.x;
    int n0 = blockIdx.x * nchunk;
    int n1 = n0 + nchunk; if (n1 > N) n1 = N;
    int j = threadIdx.x & 127;
    int half = threadIdx.x >> 7;
    float s = 0.f, m = 0.f; int gcur = -1;
    for (int n = n0 + half; n < n1; n += 2) {
        int g = batch[n];
        if (g != gcur) {
            if (gcur >= 0) {
                atomicAdd(&gsum[(size_t)gcur * HD + j], s);
                atomicMax(&gmax[(size_t)gcur * HD + j], __float_as_uint(m));
            }
            gcur = g; s = 0.f; m = 0.f;
        }
        float v = h[(size_t)n * HD + j];
        s += v; m = fmaxf(m, v);
    }
    if (gcur >= 0) {
        atomicAdd(&gsum[(size_t)gcur * HD + j], s);
        atomicMax(&gmax[(size_t)gcur * HD + j], __float_as_uint(m));
    }
}

__global__ __launch_bounds__(128) void k_cls(
    const float* __restrict__ gsum, const float* __restrict__ gmax,
    const int* __restrict__ gcnt,
    const float* __restrict__ W1, const float* __restrict__ b1,
    const float* __restrict__ W2, const float* __restrict__ b2,
    const float* __restrict__ W3, const float* __restrict__ b3,
    float* __restrict__ out)
{
    __shared__ float rep[256];
    __shared__ float z1[128];
    __shared__ float z2[64];
    const int g = blockIdx.x;
    const int j = threadIdx.x;
    float cntf = (float)gcnt[g];
    rep[j]       = gsum[(size_t)g * HD + j] / fmaxf(cntf, 1.f);
    rep[128 + j] = gmax[(size_t)g * HD + j];
    __syncthreads();
    float a = 0.f;
    for (int k = 0; k < 256; ++k) a = fmaf(rep[k], W1[(size_t)k * 128 + j], a);
    z1[j] = fmaxf(a + b1[j], 0.f);
    __syncthreads();
    if (j < 64) {
        float b = 0.f;
        for (int k = 0; k < 128; ++k) b = fmaf(z1[k], W2[(size_t)k * 64 + j], b);
        z2[j] = fmaxf(b + b2[j], 0.f);
    }
    __syncthreads();
    if (j < 2) {
        float c = 0.f;
        for (int k = 0; k < 64; ++k) c = fmaf(z2[k], W3[(size_t)k * 2 + j], c);
        out[(size_t)g * 2 + j] = c + b3[j];
    }
}

extern "C" void kernel_launch(void* const* d_in, const int* in_sizes, int n_in,
                              void* d_out, int out_size, void* d_ws, size_t ws_size,
                              hipStream_t stream) {
    const float* x      = (const float*)d_in[0];
    const float* ea     = (const float*)d_in[1];
    const int*   ei     = (const int*)d_in[2];
    const int*   batch  = (const int*)d_in[3];
    const float* emb_W  = (const float*)d_in[4];
    const float* emb_b  = (const float*)d_in[5];
    const float* msg_W1 = (const float*)d_in[6];
    const float* msg_b1 = (const float*)d_in[7];
    const float* msg_W2 = (const float*)d_in[8];
    const float* msg_b2 = (const float*)d_in[9];
    const float* upd_W1 = (const float*)d_in[10];
    const float* upd_b1 = (const float*)d_in[11];
    const float* upd_W2 = (const float*)d_in[12];
    const float* upd_b2 = (const float*)d_in[13];
    const float* cW1 = (const float*)d_in[14];
    const float* cb1 = (const float*)d_in[15];
    const float* cW2 = (const float*)d_in[16];
    const float* cb2 = (const float*)d_in[17];
    const float* cW3 = (const float*)d_in[18];
    const float* cb3 = (const float*)d_in[19];

    const int N = in_sizes[0] / 64;
    const int E = in_sizes[1] / 16;
    const int G = 256, L = 3;
    const int* src = ei;
    const int* dst = ei + E;

    char* w = (char*)d_ws;
    size_t off = 0;
    auto alloc = [&](size_t bytes) -> void* {
        void* p = w + off;
        off += (bytes + 255) & ~(size_t)255;
        return p;
    };
    float* X0 = (float*)alloc((size_t)N * HD * 4);   // h
    float* Pb = (float*)alloc((size_t)N * HD * 4);   // P; reused as U
    float* Qb = (float*)alloc((size_t)N * HD * 4);   // Q
    float* S  = (float*)alloc((size_t)N * HD * 4);   // edge aggregation
    float* Wcomb = (float*)alloc((size_t)L * 256 * HD * 4);
    float* bvec2 = (float*)alloc((size_t)L * HD * 4);
    int*   degi = (int*)alloc((size_t)N * 4);
    float* degf = (float*)alloc((size_t)N * 4);
    int*   rowptr = (int*)alloc((size_t)(N + 1) * 4);
    int*   cursor = (int*)alloc((size_t)N * 4);
    int*   gcnt   = (int*)alloc(256 * 4);
    float* gsum   = (float*)alloc((size_t)G * HD * 4);
    float* gmax   = (float*)alloc((size_t)G * HD * 4);
    int*   csr_src = (int*)alloc((size_t)E * 4);
    int*   csr_eid = (int*)alloc((size_t)E * 4);
    float* ea_p = nullptr;
    if (ws_size && off + (size_t)E * 16 * 4 + 256 <= ws_size)
        ea_p = (float*)alloc((size_t)E * 16 * 4);
    float* U = Pb;
    (void)n_in; (void)out_size;

    hipMemsetAsync(degi, 0, (size_t)N * 4, stream);
    hipMemsetAsync(gcnt, 0, 256 * 4, stream);
    hipMemsetAsync(gsum, 0, (size_t)G * HD * 4, stream);
    hipMemsetAsync(gmax, 0, (size_t)G * HD * 4, stream);

    // CSR + folds (reused across layers)
    k_deg<<<(E + 255) / 256, 256, 0, stream>>>(dst, degi, E);
    k_hist<<<(N + 255) / 256, 256, 0, stream>>>(batch, gcnt, N);
    k_rowptr<<<1, 1024, 0, stream>>>(degi, rowptr, cursor, degf, N);
    k_scatter<<<(E + 255) / 256, 256, 0, stream>>>(dst, src, cursor, csr_src, csr_eid, E);
    if (ea_p)
        k_permEA<<<(int)(((long long)E * 4 + 255) / 256), 256, 0, stream>>>(ea, csr_eid, ea_p, E);
    for (int l = 0; l < L; ++l)
        hipMemcpyAsync(Wcomb + (size_t)l * 256 * HD,
                       upd_W1 + (size_t)l * 256 * HD,
                       (size_t)HD * HD * 4, hipMemcpyDeviceToDevice, stream);
    k_foldW<<<L * 8, 256, 0, stream>>>(msg_W2, upd_W1, Wcomb);
    k_foldb<<<L, 128, 0, stream>>>(msg_b2, upd_W1, bvec2);

    const int gb = (N + 63) / 64;
    // embed: h = x @ emb_W + emb_b
    k_gemm<128><<<gb, 256, 0, stream>>>(x, 64, nullptr, 0, emb_W, nullptr,
                                        emb_b, nullptr, nullptr, 0, X0, nullptr, N);

    for (int l = 0; l < L; ++l) {
        const float* W1 = msg_W1 + (size_t)l * 272 * HD;
        const float* U2 = upd_W2 + (size_t)l * HD * HD;
        // P = h@Wa + b1 ; Q = h@Wb
        k_gemm<256><<<gb, 256, 0, stream>>>(X0, HD, nullptr, 0, W1, W1 + 128 * HD,
                                            msg_b1 + (size_t)l * HD, nullptr, nullptr,
                                            0, Pb, Qb, N);
        // S[n] = sum_in relu(P[n] + Q[src] + ea@Wc)
        if (ea_p)
            k_edge<true><<<(N + 3) / 4, 256, 0, stream>>>(Pb, Qb, ea_p, rowptr,
                                                          csr_src, nullptr,
                                                          W1 + 256 * HD, S, N);
        else
            k_edge<false><<<(N + 3) / 4, 256, 0, stream>>>(Pb, Qb, ea, rowptr,
                                                           csr_src, csr_eid,
                                                           W1 + 256 * HD, S, N);
        // U = relu(h@U1a + S@(W2@U1b) + b1u + deg*(b2@U1b))
        k_gemm<128><<<gb, 256, 0, stream>>>(X0, HD, S, HD,
                                            Wcomb + (size_t)l * 256 * HD, nullptr,
                                            upd_b1 + (size_t)l * HD,
                                            bvec2 + (size_t)l * HD, degf,
                                            1, U, nullptr, N);
        // h = relu(U @ U2 + b2u)
        k_gemm<128><<<gb, 256, 0, stream>>>(U, HD, nullptr, 0, U2, nullptr,
                                            upd_b2 + (size_t)l * HD, nullptr, nullptr,
                                            1, X0, nullptr, N);
    }

    k_pool2<<<1024, 256, 0, stream>>>(X0, batch, gsum, (unsigned int*)gmax, N);
    k_cls<<<G, 128, 0, stream>>>(gsum, gmax, gcnt, cW1, cb1, cW2, cb2, cW3, cb3,
                                 (float*)d_out);
}